// Round 2
// baseline (441.378 us; speedup 1.0000x reference)
//
#include <hip/hip_runtime.h>

// Output [N,C,D,H,W] = [2,32,48,128,256] fp32 (402.7 MB) — pure store-bandwidth problem.
// cost[nc,d,h,w] = (w >= d) ? l[nc,h,w] - r[nc,h,w-d] : 1.0f
//
// Decomposition: one block per (nc, d) output PLANE (3072 blocks). Block b writes the
// contiguous byte range [b*128KB, (b+1)*128KB) — the grid covers the output buffer
// exactly linearly, matching the access pattern of the 6.27 TB/s fillBuffer dispatch.
// Inputs (16.8 MB total) are L2/L3-resident; re-reading them per-d costs no HBM fetch.
constexpr int N = 2, C = 32, H = 128, W = 256, D = 48;
constexpr int NC = N * C;   // 64
constexpr int W4 = W / 4;   // 64 float4 per row == one wave width

// Native clang vector type: __builtin_nontemporal_store requires it (HIP's
// float4 wrapper class is rejected). Same 16-byte layout.
typedef float f32x4 __attribute__((ext_vector_type(4)));

// r[w-d] per lane = aligned float4 at (lane - q) plus spill-over from (lane - q - 1),
// where q = d>>2, S = d&3. S is block-uniform -> compile-time component shuffle,
// no LDS, no shfl, no divergence.
template <int S>
__device__ __forceinline__ void plane_loop(const f32x4* __restrict__ l4,
                                           const f32x4* __restrict__ r4,
                                           f32x4* __restrict__ o4,
                                           int q, int d, int lane, int wv)
{
    const int rvi = max(lane - q, 0);      // clamped: garbage lanes are masked below
    const int rmi = max(lane - q - 1, 0);
    const int w0  = lane << 2;

    #pragma unroll 4
    for (int h = wv; h < H; h += 4) {
        const int row = h * W4;
        const f32x4 lv = l4[row + lane];
        const f32x4 rv = r4[row + rvi];
        f32x4 rm = rv;                     // dead for S==0 (compiler drops the load)
        if (S != 0) rm = r4[row + rmi];

        float rs0, rs1, rs2, rs3;
        if (S == 0) { rs0 = rv.x; rs1 = rv.y; rs2 = rv.z; rs3 = rv.w; }
        if (S == 1) { rs0 = rm.w; rs1 = rv.x; rs2 = rv.y; rs3 = rv.z; }
        if (S == 2) { rs0 = rm.z; rs1 = rm.w; rs2 = rv.x; rs3 = rv.y; }
        if (S == 3) { rs0 = rm.y; rs1 = rm.z; rs2 = rm.w; rs3 = rv.x; }

        f32x4 o;
        o.x = (w0 + 0 >= d) ? lv.x - rs0 : 1.0f;
        o.y = (w0 + 1 >= d) ? lv.y - rs1 : 1.0f;
        o.z = (w0 + 2 >= d) ? lv.z - rs2 : 1.0f;
        o.w = (w0 + 3 >= d) ? lv.w - rs3 : 1.0f;

        // Nontemporal: don't let the 402 MB write stream evict the 16.8 MB of
        // L2-resident inputs that every (nc,*) block keeps re-reading.
        __builtin_nontemporal_store(o, &o4[row + lane]);
    }
}

__global__ __launch_bounds__(256) void cost_volume_kernel(
    const float* __restrict__ l,
    const float* __restrict__ r,
    f32x4* __restrict__ out)
{
    const int blk  = blockIdx.x;       // nc*D + d, 3072 blocks
    const int d    = blk % D;
    const int nc   = blk / D;
    const int t    = threadIdx.x;
    const int lane = t & 63;
    const int wv   = t >> 6;           // wave id 0..3 -> rows h = wv, wv+4, ...

    const f32x4* l4 = reinterpret_cast<const f32x4*>(l) + (size_t)nc * H * W4;
    const f32x4* r4 = reinterpret_cast<const f32x4*>(r) + (size_t)nc * H * W4;
    f32x4* o4 = out + (size_t)blk * H * W4;   // contiguous 128 KB plane per block

    const int q = d >> 2;
    switch (d & 3) {
        case 0: plane_loop<0>(l4, r4, o4, q, d, lane, wv); break;
        case 1: plane_loop<1>(l4, r4, o4, q, d, lane, wv); break;
        case 2: plane_loop<2>(l4, r4, o4, q, d, lane, wv); break;
        case 3: plane_loop<3>(l4, r4, o4, q, d, lane, wv); break;
    }
}

extern "C" void kernel_launch(void* const* d_in, const int* in_sizes, int n_in,
                              void* d_out, int out_size, void* d_ws, size_t ws_size,
                              hipStream_t stream)
{
    const float* l = (const float*)d_in[0];
    const float* r = (const float*)d_in[1];
    f32x4* out = (f32x4*)d_out;

    constexpr int GRID = NC * D;   // 3072 blocks, 256 threads each
    cost_volume_kernel<<<GRID, 256, 0, stream>>>(l, r, out);
}